// Round 9
// baseline (207.425 us; speedup 1.0000x reference)
//
#include <hip/hip_runtime.h>

// LTC cell: B=1024, I=128, N=256, 6 unfolds. Round 9.
// Round-6/8 shape (1024 thr, bb=2, grid 512 -> 2 blocks/CU, 8 waves/SIMD).
// Key change: SHARED-RCP sigmoid groups. For a 2i x 2batch tile (4 sigmoids)
// compute 4 exp2 + ONE rcp:  p_i = 1+2^t_i, q0 = p00*p10 (batch0),
// q1 = p01*p11 (batch1), R = rcp(q0*q1); 1/q0 = R*q1, 1/q1 = R*q0;
// batch0 accum: (W0*p10 + W1*p00) * (R*q1)  [exact algebra].
// Trans issue per 4 terms: 8 -> 5 (measured trans cost ~12 cyc/wave each,
// 75% of issue in rounds 4/6/8 -> this attacks the dominant pipe).
// Args via asm v_fma_mix_f32 (f16 A,B halves, f32 v); W,E via cvt.

#define LOG2E 1.44269504088896340f

constexpr int Bn = 1024;
constexpr int In = 128;
constexpr int Nn = 256;
constexpr int UNFOLDS = 6;

#if __has_builtin(__builtin_amdgcn_exp2f)
#define EXP2F(x) __builtin_amdgcn_exp2f(x)
#else
#define EXP2F(x) __exp2f(x)
#endif
#if __has_builtin(__builtin_amdgcn_rcpf)
#define RCPF(x) __builtin_amdgcn_rcpf(x)
#else
#define RCPF(x) (1.0f / (x))
#endif

__device__ __forceinline__ unsigned pack2h(float lo, float hi) {
    union { _Float16 h; unsigned short u; } a, b;
    a.h = (_Float16)lo;
    b.h = (_Float16)hi;
    return (unsigned)a.u | ((unsigned)b.u << 16);
}

// t = A*v + B where A = f16 lo half of %1, B = f16 hi half of %1, v = f32 %2.
#define MIX_AB(t, ab, v)                                                      \
    asm("v_fma_mix_f32 %0, %1, %2, %1 op_sel:[0,0,1] op_sel_hi:[1,0,1]"       \
        : "=v"(t) : "v"(ab), "v"(v))

// ---------------------------------------------------------------------------
// Pack: i-pair layout. Prec2[j*N+n] = uint4 {B0<<16|A0, E0<<16|W0,
//                                            B1<<16|A1, E1<<16|W1} (f16 bits)
// for i = 2j, 2j+1. A = -sigma*log2e, B = sigma*mu*log2e, E = W*erev.
// sigmoid(sigma*(v-mu)) = 1/(1+exp2(A*v+B)). Same for Psen2 (64 pairs).
// ---------------------------------------------------------------------------
__global__ __launch_bounds__(256) void pack_kernel(
    const float* __restrict__ mu, const float* __restrict__ sigma,
    const float* __restrict__ W, const float* __restrict__ erev,
    const float* __restrict__ smu, const float* __restrict__ ssigma,
    const float* __restrict__ sW, const float* __restrict__ serev,
    uint4* __restrict__ Prec2, uint4* __restrict__ Psen2) {
    int idx = blockIdx.x * 256 + threadIdx.x;
    if (idx < 128 * Nn) {
        int n = idx & 255, j = idx >> 8;
        int a = (2 * j) * Nn + n, b = a + Nn;
        float s0 = sigma[a], m0 = mu[a], w0 = W[a];
        float s1 = sigma[b], m1 = mu[b], w1 = W[b];
        Prec2[idx] = make_uint4(
            pack2h(-s0 * LOG2E, s0 * m0 * LOG2E), pack2h(w0, w0 * erev[a]),
            pack2h(-s1 * LOG2E, s1 * m1 * LOG2E), pack2h(w1, w1 * erev[b]));
        return;
    }
    int jdx = idx - 128 * Nn;
    if (jdx < 64 * Nn) {
        int n = jdx & 255, j = jdx >> 8;
        int a = (2 * j) * Nn + n, b = a + Nn;
        float s0 = ssigma[a], m0 = smu[a], w0 = sW[a];
        float s1 = ssigma[b], m1 = smu[b], w1 = sW[b];
        Psen2[jdx] = make_uint4(
            pack2h(-s0 * LOG2E, s0 * m0 * LOG2E), pack2h(w0, w0 * serev[a]),
            pack2h(-s1 * LOG2E, s1 * m1 * LOG2E), pack2h(w1, w1 * serev[b]));
    }
}

// 4 sigmoid terms (2 i x 2 batches) with ONE rcp.
// hw = {B0A0, E0W0, B1A1, E1W1}; v4 = {v(i0,b0), v(i0,b1), v(i1,b0), v(i1,b1)}.
#define TILE4(hw, v4)                                                         \
    {                                                                         \
        float t00, t01, t10, t11;                                             \
        MIX_AB(t00, (hw).x, (v4).x);                                          \
        MIX_AB(t01, (hw).x, (v4).y);                                          \
        MIX_AB(t10, (hw).z, (v4).z);                                          \
        MIX_AB(t11, (hw).z, (v4).w);                                          \
        float p00 = 1.f + EXP2F(t00);                                         \
        float p01 = 1.f + EXP2F(t01);                                         \
        float p10 = 1.f + EXP2F(t10);                                         \
        float p11 = 1.f + EXP2F(t11);                                         \
        float q0 = p00 * p10;   /* batch0 product */                          \
        float q1 = p01 * p11;   /* batch1 product */                          \
        float R = RCPF(q0 * q1);                                              \
        float r0 = R * q1;      /* = 1/q0 */                                  \
        float r1 = R * q0;      /* = 1/q1 */                                  \
        union { unsigned u; _Float16 h[2]; } c0, c1;                          \
        c0.u = (hw).y;                                                        \
        c1.u = (hw).w;                                                        \
        float W0 = (float)c0.h[0], E0 = (float)c0.h[1];                       \
        float W1 = (float)c1.h[0], E1 = (float)c1.h[1];                       \
        float s0 = fmaf(W1, p00, W0 * p10);                                   \
        float u0 = fmaf(E1, p00, E0 * p10);                                   \
        float s1 = fmaf(W1, p01, W0 * p11);                                   \
        float u1 = fmaf(E1, p01, E0 * p11);                                   \
        den0 = fmaf(s0, r0, den0);                                            \
        num0 = fmaf(u0, r0, num0);                                            \
        den1 = fmaf(s1, r1, den1);                                            \
        num1 = fmaf(u1, r1, num1);                                            \
    }

// ---------------------------------------------------------------------------
// Fused LTC kernel: sensory + 6 unfolds. Grid 512 x 1024 thr.
// Block owns 2 batches x all 256 n. thread = (n = tid&255, ih = tid>>8).
// ---------------------------------------------------------------------------
__global__ __launch_bounds__(1024, 8) void ltc_fused_kernel(
    const float* __restrict__ inputs, const float* __restrict__ state,
    const float* __restrict__ input_w, const float* __restrict__ input_b,
    const uint4* __restrict__ Psen2, const uint4* __restrict__ Prec2,
    const float* __restrict__ vleak, const float* __restrict__ gleak,
    const float* __restrict__ cmt, float* __restrict__ out) {
    __shared__ float4 vt4[Nn / 2];       // [j] = {v2j_b0, v2j_b1, v2j1_b0, v2j1_b1}, 2 KB
    __shared__ float4 xs4[In / 2];       // same for sensory x, 1 KB
    __shared__ float2 part[4][2][Nn];    // [ih][bb][n], 16 KB

    const int tid = threadIdx.x;
    const int b0 = blockIdx.x * 2;
    const int n = tid & 255;
    const int ih = tid >> 8;

    float vp = 0.f, g = 0.f, c = 0.f, gvl = 0.f;
    if (ih < 2) {
        vp = state[(b0 + ih) * Nn + n];   // coalesced
        ((float*)vt4)[(n >> 1) * 4 + (n & 1) * 2 + ih] = vp;
        g = gleak[n];
        c = cmt[n];
        gvl = g * vleak[n];
    }
    if (tid < 256) {                      // xs: 128 i x 2 bb
        int i = tid & 127, bb = tid >> 7;
        ((float*)xs4)[(i >> 1) * 4 + (i & 1) * 2 + bb] =
            inputs[(b0 + bb) * In + i] * input_w[i] + input_b[i];
    }
    __syncthreads();

    // ---- sensory: 16 i-pairs per ih ----
    float sens_n = 0.f, sens_d = 0.f;
    {
        float num0 = 0.f, num1 = 0.f, den0 = 0.f, den1 = 0.f;
        const uint4* __restrict__ p = Psen2 + n;
        const int j0 = ih * 16;
#pragma unroll 8
        for (int j = j0; j < j0 + 16; ++j) {
            uint4 hw = p[j * Nn];   // coalesced dwordx4
            float4 v4 = xs4[j];     // ds_read_b128 broadcast
            TILE4(hw, v4);
        }
        part[ih][0][n] = make_float2(num0, den0);
        part[ih][1][n] = make_float2(num1, den1);
        __syncthreads();
        if (ih < 2) {
#pragma unroll
            for (int s = 0; s < 4; ++s) {
                float2 v = part[s][ih][n];
                sens_n += v.x;
                sens_d += v.y;
            }
        }
    }

    // ---- 6 unfolds: 32 i-pairs per ih ----
    const uint4* __restrict__ p = Prec2 + n;
    for (int s = 0; s < UNFOLDS; ++s) {
        __syncthreads();  // vt4 updated & part free
        float num0 = 0.f, num1 = 0.f, den0 = 0.f, den1 = 0.f;
        const int j0 = ih * 32;
#pragma unroll 8
        for (int j = j0; j < j0 + 32; ++j) {
            uint4 hw = p[j * Nn];   // coalesced dwordx4 (L2-resident stream)
            float4 v4 = vt4[j];     // ds_read_b128 broadcast
            TILE4(hw, v4);
        }
        part[ih][0][n] = make_float2(num0, den0);
        part[ih][1][n] = make_float2(num1, den1);
        __syncthreads();
        if (ih < 2) {
            float wn = sens_n, wd = sens_d;
#pragma unroll
            for (int s2 = 0; s2 < 4; ++s2) {
                float2 v = part[s2][ih][n];
                wn += v.x;
                wd += v.y;
            }
            float res = (fmaf(c, vp, gvl) + wn) * RCPF(c + g + wd);
            vp = res;
            if (s == UNFOLDS - 1)
                out[(b0 + ih) * Nn + n] = res;   // coalesced
            else
                ((float*)vt4)[(n >> 1) * 4 + (n & 1) * 2 + ih] = res;
        }
    }
}

// ---------------------------------------------------------------------------
extern "C" void kernel_launch(void* const* d_in, const int* in_sizes, int n_in,
                              void* d_out, int out_size, void* d_ws, size_t ws_size,
                              hipStream_t stream) {
    const float* inputs   = (const float*)d_in[0];
    const float* state    = (const float*)d_in[1];
    const float* input_w  = (const float*)d_in[2];
    const float* input_b  = (const float*)d_in[3];
    const float* smu      = (const float*)d_in[4];
    const float* ssigma   = (const float*)d_in[5];
    const float* sW       = (const float*)d_in[6];
    const float* serev    = (const float*)d_in[7];
    const float* mu       = (const float*)d_in[8];
    const float* sigma    = (const float*)d_in[9];
    const float* W        = (const float*)d_in[10];
    const float* erev     = (const float*)d_in[11];
    const float* vleak    = (const float*)d_in[12];
    const float* gleak    = (const float*)d_in[13];
    const float* cmt      = (const float*)d_in[14];
    float* out = (float*)d_out;

    // Workspace: Prec2 512 KiB | Psen2 256 KiB
    char* ws = (char*)d_ws;
    uint4* Prec2 = (uint4*)ws;
    uint4* Psen2 = (uint4*)(ws + (512u << 10));

    pack_kernel<<<(128 * Nn + 64 * Nn + 255) / 256, 256, 0, stream>>>(
        mu, sigma, W, erev, smu, ssigma, sW, serev, Prec2, Psen2);

    ltc_fused_kernel<<<Bn / 2, 1024, 0, stream>>>(
        inputs, state, input_w, input_b, Psen2, Prec2, vleak, gleak, cmt, out);
}